// Round 1
// baseline (10085.735 us; speedup 1.0000x reference)
//
#include <hip/hip_runtime.h>
#include <hip/hip_bf16.h>
#include <cstdint>

#define D_MODEL 512
#define NHEAD   8
#define DKH     64
#define NLAYER  6
#define BATCH   16
#define SEQ     128
#define MEMS    196
#define NROWS   (BATCH*SEQ)   // 2048
#define MROWS   (BATCH*MEMS)  // 3136

// ---------------- embedding + positional ----------------
__global__ __launch_bounds__(128) void embed_kernel(
    const int* __restrict__ x, const float* __restrict__ emb,
    const float* __restrict__ pos, float* __restrict__ h)
{
    const int row = blockIdx.x;          // b*SEQ + s
    const int s   = row & (SEQ - 1);
    const int tok = x[row];
    const int c   = threadIdx.x * 4;
    const float4 e = *(const float4*)(emb + (size_t)tok * D_MODEL + c);
    const float4 p = *(const float4*)(pos + (size_t)s   * D_MODEL + c);
    float4 o;
    o.x = e.x + p.x; o.y = e.y + p.y; o.z = e.z + p.z; o.w = e.w + p.w;
    *(float4*)(h + (size_t)row * D_MODEL + c) = o;
}

// ---------------- generic tiled fp32 GEMM: C = A(NxK) @ W(KxKo) + bias, opt relu
#define BM 64
#define BN 64
#define BK 16
__global__ __launch_bounds__(256) void gemm_kernel(
    const float* __restrict__ A, const float* __restrict__ W,
    const float* __restrict__ bias, float* __restrict__ C,
    int N, int K, int Ko, int relu)
{
    __shared__ float As[BK][BM + 4];   // +4 keeps float4 alignment (68*4 B rows)
    __shared__ float Bs[BK][BN + 4];
    const int tid = threadIdx.x;
    const int tx = tid & 15, ty = tid >> 4;
    const int m0 = blockIdx.y * BM, n0 = blockIdx.x * BN;
    float acc[4][4] = {};

    for (int k0 = 0; k0 < K; k0 += BK) {
        #pragma unroll
        for (int t = tid; t < BM * BK; t += 256) {
            const int r = t >> 4, c = t & 15;
            As[c][r] = A[(size_t)(m0 + r) * K + (k0 + c)];
        }
        #pragma unroll
        for (int t = tid; t < BK * BN; t += 256) {
            const int r = t >> 6, c = t & 63;
            Bs[r][c] = W[(size_t)(k0 + r) * Ko + (n0 + c)];
        }
        __syncthreads();
        #pragma unroll
        for (int kk = 0; kk < BK; ++kk) {
            const float4 a4 = *(const float4*)&As[kk][ty * 4];
            const float4 b4 = *(const float4*)&Bs[kk][tx * 4];
            const float a[4] = {a4.x, a4.y, a4.z, a4.w};
            const float b[4] = {b4.x, b4.y, b4.z, b4.w};
            #pragma unroll
            for (int i = 0; i < 4; ++i)
                #pragma unroll
                for (int j = 0; j < 4; ++j)
                    acc[i][j] = fmaf(a[i], b[j], acc[i][j]);
        }
        __syncthreads();
    }
    #pragma unroll
    for (int i = 0; i < 4; ++i) {
        const int m = m0 + ty * 4 + i;
        #pragma unroll
        for (int j = 0; j < 4; ++j) {
            const int n = n0 + tx * 4 + j;
            float v = acc[i][j] + bias[n];
            if (relu) v = fmaxf(v, 0.f);
            C[(size_t)m * Ko + n] = v;
        }
    }
}

// ---------------- fused scores+softmax+PV, one block per (b, head, query row)
__global__ __launch_bounds__(256) void attn_kernel(
    const float* __restrict__ Q, const float* __restrict__ K,
    const float* __restrict__ V, float* __restrict__ O,
    int Sk, int causal)
{
    const int i  = blockIdx.x;   // query position
    const int hh = blockIdx.y;   // head
    const int b  = blockIdx.z;
    const int tid = threadIdx.x;

    __shared__ float qs[DKH];
    __shared__ float p[256];
    __shared__ float red[256];
    __shared__ float pv[4][DKH];

    const size_t qoff = ((size_t)(b * SEQ + i)) * D_MODEL + hh * DKH;
    if (tid < DKH) qs[tid] = Q[qoff + tid];
    __syncthreads();

    float s = -1e30f;
    const bool valid = (tid < Sk) && !(causal && tid > i);
    if (valid) {
        const float* krow = K + ((size_t)(b * Sk + tid)) * D_MODEL + hh * DKH;
        float a = 0.f;
        #pragma unroll
        for (int d = 0; d < DKH; ++d) a = fmaf(qs[d], krow[d], a);
        s = a * (1.0f / 64.0f);   // ref divides by d_k, not sqrt(d_k)
    }
    red[tid] = s;
    __syncthreads();
    #pragma unroll
    for (int off = 128; off > 0; off >>= 1) {
        if (tid < off) red[tid] = fmaxf(red[tid], red[tid + off]);
        __syncthreads();
    }
    const float mx = red[0];
    __syncthreads();
    const float e = valid ? __expf(s - mx) : 0.f;
    p[tid]   = e;
    red[tid] = e;
    __syncthreads();
    #pragma unroll
    for (int off = 128; off > 0; off >>= 1) {
        if (tid < off) red[tid] += red[tid + off];
        __syncthreads();
    }
    const float inv = 1.0f / red[0];

    const int d = tid & (DKH - 1);
    const int c = tid >> 6;
    float a = 0.f;
    const int jend = min((c + 1) * 64, Sk);
    for (int j = c * 64; j < jend; ++j)
        a = fmaf(p[j], V[((size_t)(b * Sk + j)) * D_MODEL + hh * DKH + d], a);
    pv[c][d] = a;
    __syncthreads();
    if (tid < DKH) {
        const float o = (pv[0][tid] + pv[1][tid] + pv[2][tid] + pv[3][tid]) * inv;
        O[qoff + tid] = o;
    }
}

// ---------------- residual add + layernorm: Y = LN(X + R)*g + b
__global__ __launch_bounds__(256) void ln_kernel(
    const float* __restrict__ X, const float* __restrict__ R,
    const float* __restrict__ g, const float* __restrict__ bb,
    float* __restrict__ Y, float eps)
{
    const int row = blockIdx.x;
    const int tid = threadIdx.x;
    __shared__ float red[256];
    const size_t base = (size_t)row * D_MODEL;
    const float x0 = X[base + tid]       + R[base + tid];
    const float x1 = X[base + 256 + tid] + R[base + 256 + tid];
    red[tid] = x0 + x1;
    __syncthreads();
    #pragma unroll
    for (int off = 128; off > 0; off >>= 1) {
        if (tid < off) red[tid] += red[tid + off];
        __syncthreads();
    }
    const float mu = red[0] * (1.0f / D_MODEL);
    __syncthreads();
    const float d0 = x0 - mu, d1 = x1 - mu;
    red[tid] = d0 * d0 + d1 * d1;
    __syncthreads();
    #pragma unroll
    for (int off = 128; off > 0; off >>= 1) {
        if (tid < off) red[tid] += red[tid + off];
        __syncthreads();
    }
    const float var  = red[0] * (1.0f / D_MODEL);
    const float rstd = rsqrtf(var + eps);
    Y[base + tid]       = d0 * rstd * g[tid]       + bb[tid];
    Y[base + 256 + tid] = d1 * rstd * g[256 + tid] + bb[256 + tid];
}

extern "C" void kernel_launch(void* const* d_in, const int* in_sizes, int n_in,
                              void* d_out, int out_size, void* d_ws, size_t ws_size,
                              hipStream_t stream)
{
    // setup_inputs() dict order:
    const int*   x      = (const int*)  d_in[0];
    const float* memory = (const float*)d_in[1];
    // d_in[2] = mask (int32) — exactly causal tril; handled analytically
    const float* emb    = (const float*)d_in[3];
    const float* pos    = (const float*)d_in[4];
    const float* sa_qw  = (const float*)d_in[5];
    const float* sa_kw  = (const float*)d_in[6];
    const float* sa_vw  = (const float*)d_in[7];
    const float* sa_ow  = (const float*)d_in[8];
    const float* sa_qb  = (const float*)d_in[9];
    const float* sa_kb  = (const float*)d_in[10];
    const float* sa_vb  = (const float*)d_in[11];
    const float* sa_ob  = (const float*)d_in[12];
    const float* sa_lnb = (const float*)d_in[13];
    const float* sa_lng = (const float*)d_in[14];
    const float* ca_qw  = (const float*)d_in[15];
    const float* ca_kw  = (const float*)d_in[16];
    const float* ca_vw  = (const float*)d_in[17];
    const float* ca_ow  = (const float*)d_in[18];
    const float* ca_qb  = (const float*)d_in[19];
    const float* ca_kb  = (const float*)d_in[20];
    const float* ca_vb  = (const float*)d_in[21];
    const float* ca_ob  = (const float*)d_in[22];
    const float* ca_lnb = (const float*)d_in[23];
    const float* ca_lng = (const float*)d_in[24];
    const float* ff_w1  = (const float*)d_in[25];
    const float* ff_b1  = (const float*)d_in[26];
    const float* ff_w2  = (const float*)d_in[27];
    const float* ff_b2  = (const float*)d_in[28];
    const float* ff_lng = (const float*)d_in[29];
    const float* ff_lnb = (const float*)d_in[30];
    const float* logit_w= (const float*)d_in[31];
    const float* logit_b= (const float*)d_in[32];

    float* out = (float*)d_out;
    // persistent residual stream lives in ws (4 MB); all big scratch lives in
    // d_out (262 MB) which is dead until the final logit GEMM overwrites it.
    float* h    = (float*)d_ws;                         // 2048x512
    float* q    = out;                                  // 2048x512
    float* k    = q    + (size_t)NROWS * D_MODEL;       // 3136x512 capacity
    float* v    = k    + (size_t)MROWS * D_MODEL;       // 3136x512 capacity
    float* att  = v    + (size_t)MROWS * D_MODEL;       // 2048x512
    float* proj = att  + (size_t)NROWS * D_MODEL;       // 2048x512
    float* ffh  = proj + (size_t)NROWS * D_MODEL;       // 2048x2048

    embed_kernel<<<NROWS, 128, 0, stream>>>(x, emb, pos, h);

    const dim3 g512(D_MODEL / BN, NROWS / BM);       // 8 x 32
    const dim3 gmem(D_MODEL / BN, MROWS / BM);       // 8 x 49
    const dim3 gff1(2048 / BN, NROWS / BM);          // 32 x 32
    const dim3 gattn(SEQ, NHEAD, BATCH);             // 128 x 8 x 16

    for (int l = 0; l < NLAYER; ++l) {
        const size_t w2 = (size_t)l * D_MODEL * D_MODEL;
        const size_t b1 = (size_t)l * D_MODEL;
        // ---- masked self-attention ----
        gemm_kernel<<<g512, 256, 0, stream>>>(h, sa_qw + w2, sa_qb + b1, q, NROWS, 512, 512, 0);
        gemm_kernel<<<g512, 256, 0, stream>>>(h, sa_kw + w2, sa_kb + b1, k, NROWS, 512, 512, 0);
        gemm_kernel<<<g512, 256, 0, stream>>>(h, sa_vw + w2, sa_vb + b1, v, NROWS, 512, 512, 0);
        attn_kernel<<<gattn, 256, 0, stream>>>(q, k, v, att, SEQ, 1);
        gemm_kernel<<<g512, 256, 0, stream>>>(att, sa_ow + w2, sa_ob + b1, proj, NROWS, 512, 512, 0);
        ln_kernel<<<NROWS, 256, 0, stream>>>(proj, h, sa_lng + b1, sa_lnb + b1, h, 1e-8f);
        // ---- cross-attention over memory ----
        gemm_kernel<<<g512, 256, 0, stream>>>(h, ca_qw + w2, ca_qb + b1, q, NROWS, 512, 512, 0);
        gemm_kernel<<<gmem, 256, 0, stream>>>(memory, ca_kw + w2, ca_kb + b1, k, MROWS, 512, 512, 0);
        gemm_kernel<<<gmem, 256, 0, stream>>>(memory, ca_vw + w2, ca_vb + b1, v, MROWS, 512, 512, 0);
        attn_kernel<<<gattn, 256, 0, stream>>>(q, k, v, att, MEMS, 0);
        gemm_kernel<<<g512, 256, 0, stream>>>(att, ca_ow + w2, ca_ob + b1, proj, NROWS, 512, 512, 0);
        ln_kernel<<<NROWS, 256, 0, stream>>>(proj, h, ca_lng + b1, ca_lnb + b1, h, 1e-8f);
        // ---- feed-forward ----
        gemm_kernel<<<gff1, 256, 0, stream>>>(h, ff_w1 + (size_t)l * D_MODEL * 2048,
                                              ff_b1 + (size_t)l * 2048, ffh, NROWS, 512, 2048, 1);
        gemm_kernel<<<g512, 256, 0, stream>>>(ffh, ff_w2 + (size_t)l * 2048 * D_MODEL,
                                              ff_b2 + b1, proj, NROWS, 2048, 512, 0);
        ln_kernel<<<NROWS, 256, 0, stream>>>(proj, h, ff_lng + b1, ff_lnb + b1, h, 1e-6f);
    }
    // ---- logits: overwrites the scratch region of d_out entirely ----
    gemm_kernel<<<dim3(32000 / BN, NROWS / BM), 256, 0, stream>>>(
        h, logit_w, logit_b, out, NROWS, 512, 32000, 0);
}

// Round 2
// 5035.910 us; speedup vs baseline: 2.0028x; 2.0028x over previous
//
#include <hip/hip_runtime.h>
#include <cstdint>

#define D_MODEL 512
#define NHEAD   8
#define DKH     64
#define NLAYER  6
#define BATCH   16
#define SEQ     128
#define MEMS    196
#define NROWS   (BATCH*SEQ)   // 2048
#define MROWS   (BATCH*MEMS)  // 3136

typedef __attribute__((ext_vector_type(8))) short short8;
typedef __attribute__((ext_vector_type(4))) short short4v;
typedef __attribute__((ext_vector_type(4))) float floatx4;

__device__ __forceinline__ short f2bf(float f) {
    unsigned u = __builtin_bit_cast(unsigned, f);
    u += 0x7fffu + ((u >> 16) & 1u);            // RNE
    return (short)(u >> 16);
}

// ---------------- embedding + positional ----------------
__global__ __launch_bounds__(128) void embed_kernel(
    const int* __restrict__ x, const float* __restrict__ emb,
    const float* __restrict__ pos, float* __restrict__ h)
{
    const int row = blockIdx.x;
    const int s   = row & (SEQ - 1);
    const int tok = x[row];
    const int c   = threadIdx.x * 4;
    const float4 e = *(const float4*)(emb + (size_t)tok * D_MODEL + c);
    const float4 p = *(const float4*)(pos + (size_t)s   * D_MODEL + c);
    float4 o;
    o.x = e.x + p.x; o.y = e.y + p.y; o.z = e.z + p.z; o.w = e.w + p.w;
    *(float4*)(h + (size_t)row * D_MODEL + c) = o;
}

// ---------------- bf16-MFMA GEMM: C = A(MxK,f32) @ W(KxN,f32) + bias, opt relu
// 128x128x32 tiles, 256 thr = 4 waves, each wave a 64x64 quadrant (4x4 MFMA).
// A and W converted fp32->bf16 during LDS staging; W transposed in-register.
// XOR chunk swizzle keeps LDS frag reads at the bank-throughput floor.
#define TM 128
#define TN 128
#define TK 32
__global__ __launch_bounds__(256) void mgemm(
    const float* __restrict__ A, const float* __restrict__ W,
    const float* __restrict__ bias, float* __restrict__ C,
    int M, int K, int N, int relu)
{
    __shared__ __align__(16) short As[TM * TK];   // 8 KB
    __shared__ __align__(16) short Bs[TN * TK];   // 8 KB (stores W^T tile)
    const int tid = threadIdx.x;
    const int m0 = blockIdx.y * TM, n0 = blockIdx.x * TN;
    const int lane = tid & 63;
    const int wave = tid >> 6;
    const int wm = (wave >> 1) << 6, wn = (wave & 1) << 6;
    const int fm = lane & 15;          // frag row (A) / col (B,C)
    const int fq = lane >> 4;          // k-chunk for A/B frags; row-quad for C
    const int fsw = ((fq ^ ((fm >> 2) & 3)) << 3);  // swizzled frag chunk col

    floatx4 acc[4][4] = {};

    // A staging: thread -> row ar, 16 consecutive k at ac
    const int ar = tid >> 1, ac = (tid & 1) << 4;
    const int asw = (ar >> 2) & 3;
    const int ac0 = (((ac >> 3)    ^ asw) << 3);
    const int ac1 = ((((ac >> 3)+1) ^ asw) << 3);
    // B staging: thread -> 4x4 block at (kb, nb) of the 32x128 W tile
    const int nb = (tid & 31) << 2, kb = (tid >> 5) << 2;
    const int bsw = (((kb >> 3) ^ ((nb >> 2) & 3)) << 3) + (kb & 7);

    const int arow = min(m0 + ar, M - 1);          // clamp (M may not divide TM)
    const float* Ap = A + (size_t)arow * K + ac;
    const float* Wp = W + (size_t)kb * N + n0 + nb;

    for (int k0 = 0; k0 < K; k0 += TK) {
        const float4 a0 = *(const float4*)(Ap + k0);
        const float4 a1 = *(const float4*)(Ap + k0 + 4);
        const float4 a2 = *(const float4*)(Ap + k0 + 8);
        const float4 a3 = *(const float4*)(Ap + k0 + 12);
        const float4 w0 = *(const float4*)(Wp + (size_t)(k0    ) * N);
        const float4 w1 = *(const float4*)(Wp + (size_t)(k0 + 1) * N);
        const float4 w2 = *(const float4*)(Wp + (size_t)(k0 + 2) * N);
        const float4 w3 = *(const float4*)(Wp + (size_t)(k0 + 3) * N);
        __syncthreads();   // previous iteration's frag reads complete
        {
            const short8 av0 = { f2bf(a0.x), f2bf(a0.y), f2bf(a0.z), f2bf(a0.w),
                                 f2bf(a1.x), f2bf(a1.y), f2bf(a1.z), f2bf(a1.w) };
            const short8 av1 = { f2bf(a2.x), f2bf(a2.y), f2bf(a2.z), f2bf(a2.w),
                                 f2bf(a3.x), f2bf(a3.y), f2bf(a3.z), f2bf(a3.w) };
            *(short8*)&As[ar * TK + ac0] = av0;
            *(short8*)&As[ar * TK + ac1] = av1;
            const float wt[4][4] = {{w0.x, w0.y, w0.z, w0.w},
                                    {w1.x, w1.y, w1.z, w1.w},
                                    {w2.x, w2.y, w2.z, w2.w},
                                    {w3.x, w3.y, w3.z, w3.w}};
            #pragma unroll
            for (int j = 0; j < 4; ++j) {
                const short4v bw = { f2bf(wt[0][j]), f2bf(wt[1][j]),
                                     f2bf(wt[2][j]), f2bf(wt[3][j]) };
                *(short4v*)&Bs[(nb + j) * TK + bsw] = bw;
            }
        }
        __syncthreads();
        short8 af[4], bf[4];
        #pragma unroll
        for (int i = 0; i < 4; ++i)
            af[i] = *(const short8*)&As[(wm + i * 16 + fm) * TK + fsw];
        #pragma unroll
        for (int j = 0; j < 4; ++j)
            bf[j] = *(const short8*)&Bs[(wn + j * 16 + fm) * TK + fsw];
        #pragma unroll
        for (int i = 0; i < 4; ++i)
            #pragma unroll
            for (int j = 0; j < 4; ++j)
                acc[i][j] = __builtin_amdgcn_mfma_f32_16x16x32_bf16(
                                af[i], bf[j], acc[i][j], 0, 0, 0);
    }
    // epilogue: C/D layout col=lane&15, row=(lane>>4)*4+reg
    #pragma unroll
    for (int j = 0; j < 4; ++j) {
        const int col = n0 + wn + j * 16 + fm;
        const float bv = bias[col];
        #pragma unroll
        for (int i = 0; i < 4; ++i) {
            const int r0 = m0 + wm + i * 16 + fq * 4;
            #pragma unroll
            for (int r = 0; r < 4; ++r) {
                const int row = r0 + r;
                if (row < M) {
                    float v = acc[i][j][r] + bv;
                    if (relu) v = fmaxf(v, 0.f);
                    C[(size_t)row * N + col] = v;
                }
            }
        }
    }
}

// ---------------- fused scores+softmax+PV, one block per (b, head, query row)
__global__ __launch_bounds__(256) void attn_kernel(
    const float* __restrict__ Q, const float* __restrict__ K,
    const float* __restrict__ V, float* __restrict__ O,
    int Sk, int causal)
{
    const int i  = blockIdx.x;
    const int hh = blockIdx.y;
    const int b  = blockIdx.z;
    const int tid = threadIdx.x;

    __shared__ float qs[DKH];
    __shared__ float p[256];
    __shared__ float red[256];
    __shared__ float pv[4][DKH];

    const size_t qoff = ((size_t)(b * SEQ + i)) * D_MODEL + hh * DKH;
    if (tid < DKH) qs[tid] = Q[qoff + tid];
    __syncthreads();

    float s = -1e30f;
    const bool valid = (tid < Sk) && !(causal && tid > i);
    if (valid) {
        const float* krow = K + ((size_t)(b * Sk + tid)) * D_MODEL + hh * DKH;
        float a = 0.f;
        #pragma unroll
        for (int d = 0; d < DKH; ++d) a = fmaf(qs[d], krow[d], a);
        s = a * (1.0f / 64.0f);   // ref divides by d_k, not sqrt(d_k)
    }
    red[tid] = s;
    __syncthreads();
    #pragma unroll
    for (int off = 128; off > 0; off >>= 1) {
        if (tid < off) red[tid] = fmaxf(red[tid], red[tid + off]);
        __syncthreads();
    }
    const float mx = red[0];
    __syncthreads();
    const float e = valid ? __expf(s - mx) : 0.f;
    p[tid]   = e;
    red[tid] = e;
    __syncthreads();
    #pragma unroll
    for (int off = 128; off > 0; off >>= 1) {
        if (tid < off) red[tid] += red[tid + off];
        __syncthreads();
    }
    const float inv = 1.0f / red[0];

    const int d = tid & (DKH - 1);
    const int c = tid >> 6;
    float a = 0.f;
    const int jend = min((c + 1) * 64, Sk);
    for (int j = c * 64; j < jend; ++j)
        a = fmaf(p[j], V[((size_t)(b * Sk + j)) * D_MODEL + hh * DKH + d], a);
    pv[c][d] = a;
    __syncthreads();
    if (tid < DKH) {
        const float o = (pv[0][tid] + pv[1][tid] + pv[2][tid] + pv[3][tid]) * inv;
        O[qoff + tid] = o;
    }
}

// ---------------- residual add + layernorm: Y = LN(X + R)*g + b
__global__ __launch_bounds__(256) void ln_kernel(
    const float* __restrict__ X, const float* __restrict__ R,
    const float* __restrict__ g, const float* __restrict__ bb,
    float* __restrict__ Y, float eps)
{
    const int row = blockIdx.x;
    const int tid = threadIdx.x;
    __shared__ float red[256];
    const size_t base = (size_t)row * D_MODEL;
    const float x0 = X[base + tid]       + R[base + tid];
    const float x1 = X[base + 256 + tid] + R[base + 256 + tid];
    red[tid] = x0 + x1;
    __syncthreads();
    #pragma unroll
    for (int off = 128; off > 0; off >>= 1) {
        if (tid < off) red[tid] += red[tid + off];
        __syncthreads();
    }
    const float mu = red[0] * (1.0f / D_MODEL);
    __syncthreads();
    const float d0 = x0 - mu, d1 = x1 - mu;
    red[tid] = d0 * d0 + d1 * d1;
    __syncthreads();
    #pragma unroll
    for (int off = 128; off > 0; off >>= 1) {
        if (tid < off) red[tid] += red[tid + off];
        __syncthreads();
    }
    const float var  = red[0] * (1.0f / D_MODEL);
    const float rstd = rsqrtf(var + eps);
    Y[base + tid]       = d0 * rstd * g[tid]       + bb[tid];
    Y[base + 256 + tid] = d1 * rstd * g[256 + tid] + bb[256 + tid];
}

extern "C" void kernel_launch(void* const* d_in, const int* in_sizes, int n_in,
                              void* d_out, int out_size, void* d_ws, size_t ws_size,
                              hipStream_t stream)
{
    const int*   x      = (const int*)  d_in[0];
    const float* memory = (const float*)d_in[1];
    // d_in[2] = mask — exactly causal tril; handled analytically
    const float* emb    = (const float*)d_in[3];
    const float* pos    = (const float*)d_in[4];
    const float* sa_qw  = (const float*)d_in[5];
    const float* sa_kw  = (const float*)d_in[6];
    const float* sa_vw  = (const float*)d_in[7];
    const float* sa_ow  = (const float*)d_in[8];
    const float* sa_qb  = (const float*)d_in[9];
    const float* sa_kb  = (const float*)d_in[10];
    const float* sa_vb  = (const float*)d_in[11];
    const float* sa_ob  = (const float*)d_in[12];
    const float* sa_lnb = (const float*)d_in[13];
    const float* sa_lng = (const float*)d_in[14];
    const float* ca_qw  = (const float*)d_in[15];
    const float* ca_kw  = (const float*)d_in[16];
    const float* ca_vw  = (const float*)d_in[17];
    const float* ca_ow  = (const float*)d_in[18];
    const float* ca_qb  = (const float*)d_in[19];
    const float* ca_kb  = (const float*)d_in[20];
    const float* ca_vb  = (const float*)d_in[21];
    const float* ca_ob  = (const float*)d_in[22];
    const float* ca_lnb = (const float*)d_in[23];
    const float* ca_lng = (const float*)d_in[24];
    const float* ff_w1  = (const float*)d_in[25];
    const float* ff_b1  = (const float*)d_in[26];
    const float* ff_w2  = (const float*)d_in[27];
    const float* ff_b2  = (const float*)d_in[28];
    const float* ff_lng = (const float*)d_in[29];
    const float* ff_lnb = (const float*)d_in[30];
    const float* logit_w= (const float*)d_in[31];
    const float* logit_b= (const float*)d_in[32];

    float* out = (float*)d_out;
    float* h    = (float*)d_ws;                         // 2048x512 (persistent)
    float* q    = out;                                  // scratch inside d_out
    float* k    = q    + (size_t)NROWS * D_MODEL;
    float* v    = k    + (size_t)MROWS * D_MODEL;
    float* att  = v    + (size_t)MROWS * D_MODEL;
    float* proj = att  + (size_t)NROWS * D_MODEL;
    float* ffh  = proj + (size_t)NROWS * D_MODEL;       // 2048x2048

    embed_kernel<<<NROWS, 128, 0, stream>>>(x, emb, pos, h);

    auto gg = [](int M, int N) { return dim3(N / TN, (M + TM - 1) / TM); };
    const dim3 gattn(SEQ, NHEAD, BATCH);

    for (int l = 0; l < NLAYER; ++l) {
        const size_t w2 = (size_t)l * D_MODEL * D_MODEL;
        const size_t b1 = (size_t)l * D_MODEL;
        // ---- masked self-attention ----
        mgemm<<<gg(NROWS,512), 256, 0, stream>>>(h, sa_qw + w2, sa_qb + b1, q, NROWS, 512, 512, 0);
        mgemm<<<gg(NROWS,512), 256, 0, stream>>>(h, sa_kw + w2, sa_kb + b1, k, NROWS, 512, 512, 0);
        mgemm<<<gg(NROWS,512), 256, 0, stream>>>(h, sa_vw + w2, sa_vb + b1, v, NROWS, 512, 512, 0);
        attn_kernel<<<gattn, 256, 0, stream>>>(q, k, v, att, SEQ, 1);
        mgemm<<<gg(NROWS,512), 256, 0, stream>>>(att, sa_ow + w2, sa_ob + b1, proj, NROWS, 512, 512, 0);
        ln_kernel<<<NROWS, 256, 0, stream>>>(proj, h, sa_lng + b1, sa_lnb + b1, h, 1e-8f);
        // ---- cross-attention over memory ----
        mgemm<<<gg(NROWS,512), 256, 0, stream>>>(h, ca_qw + w2, ca_qb + b1, q, NROWS, 512, 512, 0);
        mgemm<<<gg(MROWS,512), 256, 0, stream>>>(memory, ca_kw + w2, ca_kb + b1, k, MROWS, 512, 512, 0);
        mgemm<<<gg(MROWS,512), 256, 0, stream>>>(memory, ca_vw + w2, ca_vb + b1, v, MROWS, 512, 512, 0);
        attn_kernel<<<gattn, 256, 0, stream>>>(q, k, v, att, MEMS, 0);
        mgemm<<<gg(NROWS,512), 256, 0, stream>>>(att, ca_ow + w2, ca_ob + b1, proj, NROWS, 512, 512, 0);
        ln_kernel<<<NROWS, 256, 0, stream>>>(proj, h, ca_lng + b1, ca_lnb + b1, h, 1e-8f);
        // ---- feed-forward ----
        mgemm<<<gg(NROWS,2048), 256, 0, stream>>>(h, ff_w1 + (size_t)l * D_MODEL * 2048,
                                                  ff_b1 + (size_t)l * 2048, ffh, NROWS, 512, 2048, 1);
        mgemm<<<gg(NROWS,512), 256, 0, stream>>>(ffh, ff_w2 + (size_t)l * 2048 * D_MODEL,
                                                 ff_b2 + b1, proj, NROWS, 2048, 512, 0);
        ln_kernel<<<NROWS, 256, 0, stream>>>(proj, h, ff_lng + b1, ff_lnb + b1, h, 1e-6f);
    }
    // ---- logits ----
    mgemm<<<gg(NROWS,32000), 256, 0, stream>>>(h, logit_w, logit_b, out, NROWS, 512, 32000, 0);
}